// Round 9
// baseline (70.269 us; speedup 1.0000x reference)
//
#include <hip/hip_runtime.h>
#include <math.h>

#define B 4
#define N 512
#define DIN 32
#define L 64
#define H 128
#define NB 2
#define R (B * N) // 2048 rows

// ---------------------------------------------------------------------------
// Fused: Z[row,:] = X[row,:]@proj_w + proj_b ; then ylin/xlin for rn block 0.
// 2 rows per workgroup of 256 (128 threads per row). Also zeroes out[].
__global__ void k_proj_lin(const float* __restrict__ X, const float* __restrict__ PW,
                           const float* __restrict__ PB, const float* __restrict__ w1,
                           const float* __restrict__ b1, float* __restrict__ Z,
                           float* __restrict__ ylin, float* __restrict__ xlin,
                           float* __restrict__ out) {
    int r = threadIdx.x / 128;           // local row 0/1
    int t = threadIdx.x % 128;
    int row = blockIdx.x * 2 + r;
    __shared__ float zrow[2][L];

    if (blockIdx.x == 0 && threadIdx.x < B) out[threadIdx.x] = 0.f;

    if (t < L) {
        const float* x = X + row * DIN;
        float acc = PB[t];
#pragma unroll
        for (int k = 0; k < DIN; ++k) acc += x[k] * PW[k * L + t];
        zrow[r][t] = acc;
        Z[row * L + t] = acc;
    }
    __syncthreads();
    float ay = b1[t];  // rb1 folded into ylin
    float ax = 0.f;
#pragma unroll
    for (int k = 0; k < L; ++k) {
        float zv = zrow[r][k];
        ay += zv * w1[k * H + t];
        ax += zv * w1[(L + k) * H + t];
    }
    ylin[row * H + t] = ay;
    xlin[row * H + t] = ax;
}

// ---------------------------------------------------------------------------
// hsum[b,n,h] = sum_m relu(x_lin[b,n,h] + y_lin[b,m,h])
// Chunked-sort version (proven 57.2us): 8 chunks of 64 y-values, each
// bitonic-sorted ascending independently (21 barrier rounds). Per-chunk
// suffix sums; each query = 8 independent 6-step binary searches.
// Selection is exact (relu zeros contribute exactly 0); only summation
// order differs from the naive loop.
__global__ void k_pairsort(const float* __restrict__ xlin, const float* __restrict__ ylin,
                           float* __restrict__ hsum) {
    __shared__ float ys[512];       // 8 sorted chunks of 64
    __shared__ float ss[8 * 65];    // per-chunk suffix sums, ss[c*65+64]=0
    __shared__ float csum[64];      // 8 sub-chunk (of 8) sums per chunk
    __shared__ float csuf[8 * 9];   // per-chunk suffix of sub-sums, [c][8]=0

    int t = threadIdx.x;
    int b = blockIdx.x >> 7;     // / H
    int h = blockIdx.x & 127;    // % H

    const float* ycol = ylin + (size_t)b * N * H + h;
    ys[t] = ycol[(size_t)t * H];
    ys[t + 256] = ycol[(size_t)(t + 256) * H];
    __syncthreads();

    // bitonic sort: each 64-chunk ascending. Direction from LOCAL index
    // (i & 63), so every chunk sorts ascending (k=64 phase: bit6 masked off).
    for (int k = 2; k <= 64; k <<= 1) {
        for (int j = k >> 1; j > 0; j >>= 1) {
            int i = ((t & ~(j - 1)) << 1) | (t & (j - 1));
            int p = i | j;                    // same chunk: j <= 32
            float a = ys[i], c = ys[p];
            bool up = (i & k & 63) == 0;
            if ((a > c) == up) { ys[i] = c; ys[p] = a; }
            __syncthreads();
        }
    }

    // sub-chunk sums (8 consecutive each)
    if (t < 64) {
        float s = 0.f;
        int base = t * 8;
#pragma unroll
        for (int q = 7; q >= 0; --q) s += ys[base + q];
        csum[t] = s;
    }
    __syncthreads();
    // per-chunk suffix of the 8 sub-sums (fully parallel)
    if (t < 64) {
        int c = t >> 3, s = t & 7;
        float acc = 0.f;
        for (int q = 7; q >= s; --q) acc += csum[c * 8 + q];
        csuf[c * 9 + s] = acc;
    }
    if (t < 8) csuf[t * 9 + 8] = 0.f;
    __syncthreads();
    // ss[c*65+loc] = sum_{q>=loc} ys[c*64+q]
    for (int i = t; i < 512; i += 256) {
        int c = i >> 6, loc = i & 63;
        float s = csuf[c * 9 + (loc >> 3) + 1];
        int base = c * 64;
        int e = loc | 7;
        for (int q = e; q >= loc; --q) s += ys[base + q];
        ss[c * 65 + loc] = s;
    }
    if (t < 8) ss[t * 65 + 64] = 0.f;
    __syncthreads();

    // queries for rows t and t+256: 8 independent 6-level searches each
    const float* xcol = xlin + (size_t)b * N * H + h;
    float* ocol = hsum + (size_t)b * N * H + h;
    float x0 = xcol[(size_t)t * H];
    float x1 = xcol[(size_t)(t + 256) * H];
    float v0 = -x0, v1 = -x1;
    float acc0 = 0.f, acc1 = 0.f;
    int cnt0 = 0, cnt1 = 0;
#pragma unroll
    for (int c = 0; c < 8; ++c) {
        int base = c * 64;
        int p0 = 0, p1 = 0;
#pragma unroll
        for (int s = 32; s >= 1; s >>= 1) {
            if (ys[base + p0 + s - 1] <= v0) p0 += s;
            if (ys[base + p1 + s - 1] <= v1) p1 += s;
        }
        cnt0 += 64 - p0; acc0 += ss[c * 65 + p0];
        cnt1 += 64 - p1; acc1 += ss[c * 65 + p1];
    }
    ocol[(size_t)t * H] = (float)cnt0 * x0 + acc0;
    ocol[(size_t)(t + 256) * H] = (float)cnt1 * x1 + acc1;
}

// ---------------------------------------------------------------------------
// Fused per-row tail with ASYNC weight staging (T14): each stage's global
// loads are issued into registers BEFORE the previous stage's compute, so
// L2 latency hides under the FMAs; after the barrier only the cheap
// LDS-writes remain. Compute bodies identical to the proven 57.2us kernel.
template <bool FINAL>
__global__ void k_post(const float* __restrict__ hsum, const float* __restrict__ w2,
                       const float* __restrict__ b2, const float* __restrict__ fw1,
                       const float* __restrict__ fb1, const float* __restrict__ fw2,
                       const float* __restrict__ fb2, const float* __restrict__ nw1,
                       const float* __restrict__ nb1, float* __restrict__ Z,
                       float* __restrict__ ylin, float* __restrict__ xlin,
                       const float* __restrict__ dw, const float* __restrict__ db,
                       float* __restrict__ out) {
    __shared__ float wbuf[H * L];     // 8192 floats = 32 KB (reused per stage)
    __shared__ float hl_[8][H];       // 4 KB
    __shared__ float zl[8][L];        // 2 KB
    __shared__ float tl[8][H];        // 4 KB
    __shared__ float part[4];

    int t = threadIdx.x;
    int row0 = blockIdx.x * 8;
    float4 pre[8];                    // staging registers (32 VGPRs)

    // initial staging: w2 + inputs (nothing to hide under yet)
#pragma unroll
    for (int j = 0; j < 8; ++j) pre[j] = ((const float4*)w2)[t + j * 256];
    ((float4*)hl_)[t] = ((const float4*)(hsum + (size_t)row0 * H))[t];
    if (t < 128) ((float4*)zl)[t] = ((const float4*)(Z + (size_t)row0 * L))[t];
#pragma unroll
    for (int j = 0; j < 8; ++j) ((float4*)wbuf)[t + j * 256] = pre[j];
    __syncthreads();

    // prefetch fw1 (hides under rn_update)
#pragma unroll
    for (int j = 0; j < 8; ++j) pre[j] = ((const float4*)fw1)[t + j * 256];

    // ---- rn_update: zl[r][l] += sum_k hl_[r][k]*w2[k][l] + N*b2[l]
    {
        int l = t & 63;
        int r0 = (t >> 6) * 2, r1 = r0 + 1;
        float a0 = 0.f, a1 = 0.f;
#pragma unroll
        for (int kk = 0; kk < H; kk += 4) {
            float4 h0v = *(float4*)&hl_[r0][kk];
            float4 h1v = *(float4*)&hl_[r1][kk];
            float w0 = wbuf[(kk + 0) * L + l];
            float w1v = wbuf[(kk + 1) * L + l];
            float w2v = wbuf[(kk + 2) * L + l];
            float w3 = wbuf[(kk + 3) * L + l];
            a0 += h0v.x * w0 + h0v.y * w1v + h0v.z * w2v + h0v.w * w3;
            a1 += h1v.x * w0 + h1v.y * w1v + h1v.z * w2v + h1v.w * w3;
        }
        float nb2 = (float)N * b2[l];
        zl[r0][l] += a0 + nb2;
        zl[r1][l] += a1 + nb2;
    }
    __syncthreads();
#pragma unroll
    for (int j = 0; j < 8; ++j) ((float4*)wbuf)[t + j * 256] = pre[j];
    __syncthreads();

    // prefetch fw2 (hides under fc1)
#pragma unroll
    for (int j = 0; j < 8; ++j) pre[j] = ((const float4*)fw2)[t + j * 256];

    // ---- fc1: tl[r][h] = relu(sum_l zl[r][l]*fw1[l][h] + fb1[h])
    {
        int h = t & 127;
        int rq = (t >> 7) * 4;
        float acc0 = 0.f, acc1 = 0.f, acc2 = 0.f, acc3 = 0.f;
#pragma unroll
        for (int ll = 0; ll < L; ll += 4) {
            float w0 = wbuf[(ll + 0) * H + h];
            float w1v = wbuf[(ll + 1) * H + h];
            float w2v = wbuf[(ll + 2) * H + h];
            float w3 = wbuf[(ll + 3) * H + h];
            float4 z0 = *(float4*)&zl[rq + 0][ll];
            float4 z1 = *(float4*)&zl[rq + 1][ll];
            float4 z2 = *(float4*)&zl[rq + 2][ll];
            float4 z3 = *(float4*)&zl[rq + 3][ll];
            acc0 += z0.x * w0 + z0.y * w1v + z0.z * w2v + z0.w * w3;
            acc1 += z1.x * w0 + z1.y * w1v + z1.z * w2v + z1.w * w3;
            acc2 += z2.x * w0 + z2.y * w1v + z2.z * w2v + z2.w * w3;
            acc3 += z3.x * w0 + z3.y * w1v + z3.z * w2v + z3.w * w3;
        }
        float bb = fb1[h];
        tl[rq + 0][h] = fmaxf(acc0 + bb, 0.f);
        tl[rq + 1][h] = fmaxf(acc1 + bb, 0.f);
        tl[rq + 2][h] = fmaxf(acc2 + bb, 0.f);
        tl[rq + 3][h] = fmaxf(acc3 + bb, 0.f);
    }
    __syncthreads();
#pragma unroll
    for (int j = 0; j < 8; ++j) ((float4*)wbuf)[t + j * 256] = pre[j];
    __syncthreads();

    // prefetch nw1 y-half (hides under fc2) — only needed when !FINAL
    if (!FINAL) {
#pragma unroll
        for (int j = 0; j < 8; ++j) pre[j] = ((const float4*)nw1)[t + j * 256];
    }

    // ---- fc2: zfin = zl[r][l] + sum_k tl[r][k]*fw2[k][l] + fb2[l]
    float zfin0, zfin1;
    int l_ = t & 63;
    int r0_ = (t >> 6) * 2, r1_ = r0_ + 1;
    {
        float a0 = 0.f, a1 = 0.f;
#pragma unroll
        for (int kk = 0; kk < H; kk += 4) {
            float4 t0v = *(float4*)&tl[r0_][kk];
            float4 t1v = *(float4*)&tl[r1_][kk];
            float w0 = wbuf[(kk + 0) * L + l_];
            float w1v = wbuf[(kk + 1) * L + l_];
            float w2v = wbuf[(kk + 2) * L + l_];
            float w3 = wbuf[(kk + 3) * L + l_];
            a0 += t0v.x * w0 + t0v.y * w1v + t0v.z * w2v + t0v.w * w3;
            a1 += t1v.x * w0 + t1v.y * w1v + t1v.z * w2v + t1v.w * w3;
        }
        float bb = fb2[l_];
        zfin0 = zl[r0_][l_] + a0 + bb;
        zfin1 = zl[r1_][l_] + a1 + bb;
    }

    if (FINAL) {
        // pooled decode: out[b] += sum_{r,l} z[r][l]*dw[l]  (+db once per b)
        float v = (zfin0 + zfin1) * dw[l_];
#pragma unroll
        for (int off = 32; off > 0; off >>= 1) v += __shfl_down(v, off);
        if (l_ == 0) part[t >> 6] = v;
        __syncthreads();
        if (t == 0) {
            float s = part[0] + part[1] + part[2] + part[3];
            if ((row0 % N) == 0) s += db[0];
            atomicAdd(out + row0 / N, s);
        }
        return;
    }

    // all threads done reading wbuf(fw2)/tl/zl for fc2
    __syncthreads();
    // write back Z + update LDS copy + install nw1 y-half, then one barrier
    zl[r0_][l_] = zfin0;
    zl[r1_][l_] = zfin1;
    Z[(size_t)(row0 + r0_) * L + l_] = zfin0;
    Z[(size_t)(row0 + r1_) * L + l_] = zfin1;
#pragma unroll
    for (int j = 0; j < 8; ++j) ((float4*)wbuf)[t + j * 256] = pre[j];
    __syncthreads();

    // prefetch nw1 x-half (hides under lin-y)
#pragma unroll
    for (int j = 0; j < 8; ++j) pre[j] = ((const float4*)(nw1 + L * H))[t + j * 256];

    // ---- lin-y: ylin[row][h] = nb1[h] + sum_k zl[r][k]*nw1[k][h]
    {
        int h = t & 127;
        int rq = (t >> 7) * 4;
        float acc0 = nb1[h], acc1 = acc0, acc2 = acc0, acc3 = acc0;
#pragma unroll
        for (int kk = 0; kk < L; kk += 4) {
            float w0 = wbuf[(kk + 0) * H + h];
            float w1v = wbuf[(kk + 1) * H + h];
            float w2v = wbuf[(kk + 2) * H + h];
            float w3 = wbuf[(kk + 3) * H + h];
            float4 z0 = *(float4*)&zl[rq + 0][kk];
            float4 z1 = *(float4*)&zl[rq + 1][kk];
            float4 z2 = *(float4*)&zl[rq + 2][kk];
            float4 z3 = *(float4*)&zl[rq + 3][kk];
            acc0 += z0.x * w0 + z0.y * w1v + z0.z * w2v + z0.w * w3;
            acc1 += z1.x * w0 + z1.y * w1v + z1.z * w2v + z1.w * w3;
            acc2 += z2.x * w0 + z2.y * w1v + z2.z * w2v + z2.w * w3;
            acc3 += z3.x * w0 + z3.y * w1v + z3.z * w2v + z3.w * w3;
        }
        ylin[(size_t)(row0 + rq + 0) * H + h] = acc0;
        ylin[(size_t)(row0 + rq + 1) * H + h] = acc1;
        ylin[(size_t)(row0 + rq + 2) * H + h] = acc2;
        ylin[(size_t)(row0 + rq + 3) * H + h] = acc3;
    }
    __syncthreads();
#pragma unroll
    for (int j = 0; j < 8; ++j) ((float4*)wbuf)[t + j * 256] = pre[j];
    __syncthreads();

    // ---- lin-x: xlin[row][h] = sum_k zl[r][k]*nw1[L+k][h]
    {
        int h = t & 127;
        int rq = (t >> 7) * 4;
        float acc0 = 0.f, acc1 = 0.f, acc2 = 0.f, acc3 = 0.f;
#pragma unroll
        for (int kk = 0; kk < L; kk += 4) {
            float w0 = wbuf[(kk + 0) * H + h];
            float w1v = wbuf[(kk + 1) * H + h];
            float w2v = wbuf[(kk + 2) * H + h];
            float w3 = wbuf[(kk + 3) * H + h];
            float4 z0 = *(float4*)&zl[rq + 0][kk];
            float4 z1 = *(float4*)&zl[rq + 1][kk];
            float4 z2 = *(float4*)&zl[rq + 2][kk];
            float4 z3 = *(float4*)&zl[rq + 3][kk];
            acc0 += z0.x * w0 + z0.y * w1v + z0.z * w2v + z0.w * w3;
            acc1 += z1.x * w0 + z1.y * w1v + z1.z * w2v + z1.w * w3;
            acc2 += z2.x * w0 + z2.y * w1v + z2.z * w2v + z2.w * w3;
            acc3 += z3.x * w0 + z3.y * w1v + z3.z * w2v + z3.w * w3;
        }
        xlin[(size_t)(row0 + rq + 0) * H + h] = acc0;
        xlin[(size_t)(row0 + rq + 1) * H + h] = acc1;
        xlin[(size_t)(row0 + rq + 2) * H + h] = acc2;
        xlin[(size_t)(row0 + rq + 3) * H + h] = acc3;
    }
}

extern "C" void kernel_launch(void* const* d_in, const int* in_sizes, int n_in,
                              void* d_out, int out_size, void* d_ws, size_t ws_size,
                              hipStream_t stream) {
    const float* X      = (const float*)d_in[0];
    const float* proj_w = (const float*)d_in[1];
    const float* proj_b = (const float*)d_in[2];
    const float* rn_w1  = (const float*)d_in[3];
    const float* rn_b1  = (const float*)d_in[4];
    const float* rn_w2  = (const float*)d_in[5];
    const float* rn_b2  = (const float*)d_in[6];
    const float* fc_w1  = (const float*)d_in[7];
    const float* fc_b1  = (const float*)d_in[8];
    const float* fc_w2  = (const float*)d_in[9];
    const float* fc_b2  = (const float*)d_in[10];
    const float* dec_w  = (const float*)d_in[11];
    const float* dec_b  = (const float*)d_in[12];
    float* out = (float*)d_out;

    float* ws   = (float*)d_ws;
    float* Z    = ws;                 // R*L
    float* ylin = Z + R * L;          // R*H
    float* xlin = ylin + R * H;       // R*H
    float* hsum = xlin + R * H;       // R*H

    k_proj_lin<<<R / 2, 256, 0, stream>>>(X, proj_w, proj_b, rn_w1, rn_b1, Z, ylin, xlin, out);
    k_pairsort<<<B * H, 256, 0, stream>>>(xlin, ylin, hsum);
    k_post<false><<<R / 8, 256, 0, stream>>>(hsum, rn_w2, rn_b2, fc_w1, fc_b1, fc_w2, fc_b2,
                                             rn_w1 + 2 * L * H, rn_b1 + H, Z, ylin, xlin,
                                             nullptr, nullptr, nullptr);
    k_pairsort<<<B * H, 256, 0, stream>>>(xlin, ylin, hsum);
    k_post<true><<<R / 8, 256, 0, stream>>>(hsum, rn_w2 + H * L, rn_b2 + L,
                                            fc_w1 + L * H, fc_b1 + H, fc_w2 + H * L, fc_b2 + L,
                                            nullptr, nullptr, Z, nullptr, nullptr,
                                            dec_w, dec_b, out);
}

// Round 10
// 56.915 us; speedup vs baseline: 1.2346x; 1.2346x over previous
//
#include <hip/hip_runtime.h>
#include <math.h>

#define B 4
#define N 512
#define DIN 32
#define L 64
#define H 128
#define NB 2
#define R (B * N) // 2048 rows

// ---------------------------------------------------------------------------
// Fused: Z[row,:] = X[row,:]@proj_w + proj_b ; then ylin/xlin for rn block 0.
// 2 rows per workgroup of 256 (128 threads per row). Also zeroes out[].
__global__ void k_proj_lin(const float* __restrict__ X, const float* __restrict__ PW,
                           const float* __restrict__ PB, const float* __restrict__ w1,
                           const float* __restrict__ b1, float* __restrict__ Z,
                           float* __restrict__ ylin, float* __restrict__ xlin,
                           float* __restrict__ out) {
    int r = threadIdx.x / 128;           // local row 0/1
    int t = threadIdx.x % 128;
    int row = blockIdx.x * 2 + r;
    __shared__ float zrow[2][L];

    if (blockIdx.x == 0 && threadIdx.x < B) out[threadIdx.x] = 0.f;

    if (t < L) {
        const float* x = X + row * DIN;
        float acc = PB[t];
#pragma unroll
        for (int k = 0; k < DIN; ++k) acc += x[k] * PW[k * L + t];
        zrow[r][t] = acc;
        Z[row * L + t] = acc;
    }
    __syncthreads();
    float ay = b1[t];  // rb1 folded into ylin
    float ax = 0.f;
#pragma unroll
    for (int k = 0; k < L; ++k) {
        float zv = zrow[r][k];
        ay += zv * w1[k * H + t];
        ax += zv * w1[(L + k) * H + t];
    }
    ylin[row * H + t] = ay;
    xlin[row * H + t] = ax;
}

// ---------------------------------------------------------------------------
// hsum[b,n,h] = sum_m relu(x_lin[b,n,h] + y_lin[b,m,h])
// Chunked-sort version (proven 57.2us): 8 chunks of 64 y-values, each
// bitonic-sorted ascending independently (21 barrier rounds). Per-chunk
// suffix sums; each query = 8 independent 6-step binary searches.
// Selection is exact (relu zeros contribute exactly 0); only summation
// order differs from the naive loop.
__global__ void k_pairsort(const float* __restrict__ xlin, const float* __restrict__ ylin,
                           float* __restrict__ hsum) {
    __shared__ float ys[512];       // 8 sorted chunks of 64
    __shared__ float ss[8 * 65];    // per-chunk suffix sums, ss[c*65+64]=0
    __shared__ float csum[64];      // 8 sub-chunk (of 8) sums per chunk
    __shared__ float csuf[8 * 9];   // per-chunk suffix of sub-sums, [c][8]=0

    int t = threadIdx.x;
    int b = blockIdx.x >> 7;     // / H
    int h = blockIdx.x & 127;    // % H

    const float* ycol = ylin + (size_t)b * N * H + h;
    ys[t] = ycol[(size_t)t * H];
    ys[t + 256] = ycol[(size_t)(t + 256) * H];
    __syncthreads();

    // bitonic sort: each 64-chunk ascending. Direction from LOCAL index
    // (i & 63), so every chunk sorts ascending (k=64 phase: bit6 masked off).
    for (int k = 2; k <= 64; k <<= 1) {
        for (int j = k >> 1; j > 0; j >>= 1) {
            int i = ((t & ~(j - 1)) << 1) | (t & (j - 1));
            int p = i | j;                    // same chunk: j <= 32
            float a = ys[i], c = ys[p];
            bool up = (i & k & 63) == 0;
            if ((a > c) == up) { ys[i] = c; ys[p] = a; }
            __syncthreads();
        }
    }

    // sub-chunk sums (8 consecutive each)
    if (t < 64) {
        float s = 0.f;
        int base = t * 8;
#pragma unroll
        for (int q = 7; q >= 0; --q) s += ys[base + q];
        csum[t] = s;
    }
    __syncthreads();
    // per-chunk suffix of the 8 sub-sums (fully parallel)
    if (t < 64) {
        int c = t >> 3, s = t & 7;
        float acc = 0.f;
        for (int q = 7; q >= s; --q) acc += csum[c * 8 + q];
        csuf[c * 9 + s] = acc;
    }
    if (t < 8) csuf[t * 9 + 8] = 0.f;
    __syncthreads();
    // ss[c*65+loc] = sum_{q>=loc} ys[c*64+q]
    for (int i = t; i < 512; i += 256) {
        int c = i >> 6, loc = i & 63;
        float s = csuf[c * 9 + (loc >> 3) + 1];
        int base = c * 64;
        int e = loc | 7;
        for (int q = e; q >= loc; --q) s += ys[base + q];
        ss[c * 65 + loc] = s;
    }
    if (t < 8) ss[t * 65 + 64] = 0.f;
    __syncthreads();

    // queries for rows t and t+256: 8 independent 6-level searches each
    const float* xcol = xlin + (size_t)b * N * H + h;
    float* ocol = hsum + (size_t)b * N * H + h;
    float x0 = xcol[(size_t)t * H];
    float x1 = xcol[(size_t)(t + 256) * H];
    float v0 = -x0, v1 = -x1;
    float acc0 = 0.f, acc1 = 0.f;
    int cnt0 = 0, cnt1 = 0;
#pragma unroll
    for (int c = 0; c < 8; ++c) {
        int base = c * 64;
        int p0 = 0, p1 = 0;
#pragma unroll
        for (int s = 32; s >= 1; s >>= 1) {
            if (ys[base + p0 + s - 1] <= v0) p0 += s;
            if (ys[base + p1 + s - 1] <= v1) p1 += s;
        }
        cnt0 += 64 - p0; acc0 += ss[c * 65 + p0];
        cnt1 += 64 - p1; acc1 += ss[c * 65 + p1];
    }
    ocol[(size_t)t * H] = (float)cnt0 * x0 + acc0;
    ocol[(size_t)(t + 256) * H] = (float)cnt1 * x1 + acc1;
}

// ---------------------------------------------------------------------------
// Fused per-row tail: Z += hsum@w2 + N*b2 ; Z += relu(Z@fw1+fb1)@fw2 + fb2 ;
// then either lin for the NEXT rn block (FINAL=false) or the pooled decode
// dot into out[b] (FINAL=true). 8 rows per 256-thread wg, weights staged
// stage-by-stage into a 32 KB LDS buffer.
template <bool FINAL>
__global__ void k_post(const float* __restrict__ hsum, const float* __restrict__ w2,
                       const float* __restrict__ b2, const float* __restrict__ fw1,
                       const float* __restrict__ fb1, const float* __restrict__ fw2,
                       const float* __restrict__ fb2, const float* __restrict__ nw1,
                       const float* __restrict__ nb1, float* __restrict__ Z,
                       float* __restrict__ ylin, float* __restrict__ xlin,
                       const float* __restrict__ dw, const float* __restrict__ db,
                       float* __restrict__ out) {
    __shared__ float wbuf[H * L];     // 8192 floats = 32 KB (reused per stage)
    __shared__ float hl_[8][H];       // 4 KB
    __shared__ float zl[8][L];        // 2 KB
    __shared__ float tl[8][H];        // 4 KB
    __shared__ float part[4];

    int t = threadIdx.x;
    int row0 = blockIdx.x * 8;

    // stage inputs (coalesced float4)
    ((float4*)hl_)[t] = ((const float4*)(hsum + (size_t)row0 * H))[t];          // 1024 floats
    if (t < 128) ((float4*)zl)[t] = ((const float4*)(Z + (size_t)row0 * L))[t]; // 512 floats
#pragma unroll
    for (int j = 0; j < 8; ++j)
        ((float4*)wbuf)[t + j * 256] = ((const float4*)w2)[t + j * 256];        // 8192 floats
    __syncthreads();

    // ---- rn_update: zl[r][l] += sum_k hl_[r][k]*w2[k][l] + N*b2[l]
    {
        int l = t & 63;
        int r0 = (t >> 6) * 2, r1 = r0 + 1;
        float a0 = 0.f, a1 = 0.f;
#pragma unroll
        for (int kk = 0; kk < H; kk += 4) {
            float4 h0v = *(float4*)&hl_[r0][kk];
            float4 h1v = *(float4*)&hl_[r1][kk];
            float w0 = wbuf[(kk + 0) * L + l];
            float w1v = wbuf[(kk + 1) * L + l];
            float w2v = wbuf[(kk + 2) * L + l];
            float w3 = wbuf[(kk + 3) * L + l];
            a0 += h0v.x * w0 + h0v.y * w1v + h0v.z * w2v + h0v.w * w3;
            a1 += h1v.x * w0 + h1v.y * w1v + h1v.z * w2v + h1v.w * w3;
        }
        float nb2 = (float)N * b2[l];
        zl[r0][l] += a0 + nb2;
        zl[r1][l] += a1 + nb2;
    }
    __syncthreads();
#pragma unroll
    for (int j = 0; j < 8; ++j)
        ((float4*)wbuf)[t + j * 256] = ((const float4*)fw1)[t + j * 256];
    __syncthreads();

    // ---- fc1: tl[r][h] = relu(sum_l zl[r][l]*fw1[l][h] + fb1[h])
    {
        int h = t & 127;
        int rq = (t >> 7) * 4;
        float acc0 = 0.f, acc1 = 0.f, acc2 = 0.f, acc3 = 0.f;
#pragma unroll
        for (int ll = 0; ll < L; ll += 4) {
            float w0 = wbuf[(ll + 0) * H + h];
            float w1v = wbuf[(ll + 1) * H + h];
            float w2v = wbuf[(ll + 2) * H + h];
            float w3 = wbuf[(ll + 3) * H + h];
            float4 z0 = *(float4*)&zl[rq + 0][ll];
            float4 z1 = *(float4*)&zl[rq + 1][ll];
            float4 z2 = *(float4*)&zl[rq + 2][ll];
            float4 z3 = *(float4*)&zl[rq + 3][ll];
            acc0 += z0.x * w0 + z0.y * w1v + z0.z * w2v + z0.w * w3;
            acc1 += z1.x * w0 + z1.y * w1v + z1.z * w2v + z1.w * w3;
            acc2 += z2.x * w0 + z2.y * w1v + z2.z * w2v + z2.w * w3;
            acc3 += z3.x * w0 + z3.y * w1v + z3.z * w2v + z3.w * w3;
        }
        float bb = fb1[h];
        tl[rq + 0][h] = fmaxf(acc0 + bb, 0.f);
        tl[rq + 1][h] = fmaxf(acc1 + bb, 0.f);
        tl[rq + 2][h] = fmaxf(acc2 + bb, 0.f);
        tl[rq + 3][h] = fmaxf(acc3 + bb, 0.f);
    }
    __syncthreads();
#pragma unroll
    for (int j = 0; j < 8; ++j)
        ((float4*)wbuf)[t + j * 256] = ((const float4*)fw2)[t + j * 256];
    __syncthreads();

    // ---- fc2: zl[r][l] += sum_k tl[r][k]*fw2[k][l] + fb2[l]
    float zfin0, zfin1;  // final z values (for FINAL path)
    int l_ = t & 63;
    int r0_ = (t >> 6) * 2, r1_ = r0_ + 1;
    {
        float a0 = 0.f, a1 = 0.f;
#pragma unroll
        for (int kk = 0; kk < H; kk += 4) {
            float4 t0v = *(float4*)&tl[r0_][kk];
            float4 t1v = *(float4*)&tl[r1_][kk];
            float w0 = wbuf[(kk + 0) * L + l_];
            float w1v = wbuf[(kk + 1) * L + l_];
            float w2v = wbuf[(kk + 2) * L + l_];
            float w3 = wbuf[(kk + 3) * L + l_];
            a0 += t0v.x * w0 + t0v.y * w1v + t0v.z * w2v + t0v.w * w3;
            a1 += t1v.x * w0 + t1v.y * w1v + t1v.z * w2v + t1v.w * w3;
        }
        float bb = fb2[l_];
        zfin0 = zl[r0_][l_] + a0 + bb;
        zfin1 = zl[r1_][l_] + a1 + bb;
    }

    if (FINAL) {
        // pooled decode: out[b] += sum_{r,l} z[r][l]*dw[l]  (+db once per b)
        float v = (zfin0 + zfin1) * dw[l_];
#pragma unroll
        for (int off = 32; off > 0; off >>= 1) v += __shfl_down(v, off);
        if (l_ == 0) part[t >> 6] = v;
        __syncthreads();
        if (t == 0) {
            float s = part[0] + part[1] + part[2] + part[3];
            if ((row0 % N) == 0) s += db[0];
            atomicAdd(out + row0 / N, s);
        }
        return;
    }

    // write back Z, update LDS copy, then lin for next rn block
    __syncthreads();
    zl[r0_][l_] = zfin0;
    zl[r1_][l_] = zfin1;
    Z[(size_t)(row0 + r0_) * L + l_] = zfin0;
    Z[(size_t)(row0 + r1_) * L + l_] = zfin1;
    __syncthreads();

    // lin-y: ylin[row][h] = nb1[h] + sum_k zl[r][k]*nw1[k][h]   (k = 0..L-1)
#pragma unroll
    for (int j = 0; j < 8; ++j)
        ((float4*)wbuf)[t + j * 256] = ((const float4*)nw1)[t + j * 256];
    __syncthreads();
    {
        int h = t & 127;
        int rq = (t >> 7) * 4;
        float acc0 = nb1[h], acc1 = acc0, acc2 = acc0, acc3 = acc0;
#pragma unroll
        for (int kk = 0; kk < L; kk += 4) {
            float w0 = wbuf[(kk + 0) * H + h];
            float w1v = wbuf[(kk + 1) * H + h];
            float w2v = wbuf[(kk + 2) * H + h];
            float w3 = wbuf[(kk + 3) * H + h];
            float4 z0 = *(float4*)&zl[rq + 0][kk];
            float4 z1 = *(float4*)&zl[rq + 1][kk];
            float4 z2 = *(float4*)&zl[rq + 2][kk];
            float4 z3 = *(float4*)&zl[rq + 3][kk];
            acc0 += z0.x * w0 + z0.y * w1v + z0.z * w2v + z0.w * w3;
            acc1 += z1.x * w0 + z1.y * w1v + z1.z * w2v + z1.w * w3;
            acc2 += z2.x * w0 + z2.y * w1v + z2.z * w2v + z2.w * w3;
            acc3 += z3.x * w0 + z3.y * w1v + z3.z * w2v + z3.w * w3;
        }
        ylin[(size_t)(row0 + rq + 0) * H + h] = acc0;
        ylin[(size_t)(row0 + rq + 1) * H + h] = acc1;
        ylin[(size_t)(row0 + rq + 2) * H + h] = acc2;
        ylin[(size_t)(row0 + rq + 3) * H + h] = acc3;
    }
    __syncthreads();
    // lin-x: xlin[row][h] = sum_k zl[r][k]*nw1[L+k][h]
#pragma unroll
    for (int j = 0; j < 8; ++j)
        ((float4*)wbuf)[t + j * 256] = ((const float4*)(nw1 + L * H))[t + j * 256];
    __syncthreads();
    {
        int h = t & 127;
        int rq = (t >> 7) * 4;
        float acc0 = 0.f, acc1 = 0.f, acc2 = 0.f, acc3 = 0.f;
#pragma unroll
        for (int kk = 0; kk < L; kk += 4) {
            float w0 = wbuf[(kk + 0) * H + h];
            float w1v = wbuf[(kk + 1) * H + h];
            float w2v = wbuf[(kk + 2) * H + h];
            float w3 = wbuf[(kk + 3) * H + h];
            float4 z0 = *(float4*)&zl[rq + 0][kk];
            float4 z1 = *(float4*)&zl[rq + 1][kk];
            float4 z2 = *(float4*)&zl[rq + 2][kk];
            float4 z3 = *(float4*)&zl[rq + 3][kk];
            acc0 += z0.x * w0 + z0.y * w1v + z0.z * w2v + z0.w * w3;
            acc1 += z1.x * w0 + z1.y * w1v + z1.z * w2v + z1.w * w3;
            acc2 += z2.x * w0 + z2.y * w1v + z2.z * w2v + z2.w * w3;
            acc3 += z3.x * w0 + z3.y * w1v + z3.z * w2v + z3.w * w3;
        }
        xlin[(size_t)(row0 + rq + 0) * H + h] = acc0;
        xlin[(size_t)(row0 + rq + 1) * H + h] = acc1;
        xlin[(size_t)(row0 + rq + 2) * H + h] = acc2;
        xlin[(size_t)(row0 + rq + 3) * H + h] = acc3;
    }
}

extern "C" void kernel_launch(void* const* d_in, const int* in_sizes, int n_in,
                              void* d_out, int out_size, void* d_ws, size_t ws_size,
                              hipStream_t stream) {
    const float* X      = (const float*)d_in[0];
    const float* proj_w = (const float*)d_in[1];
    const float* proj_b = (const float*)d_in[2];
    const float* rn_w1  = (const float*)d_in[3];
    const float* rn_b1  = (const float*)d_in[4];
    const float* rn_w2  = (const float*)d_in[5];
    const float* rn_b2  = (const float*)d_in[6];
    const float* fc_w1  = (const float*)d_in[7];
    const float* fc_b1  = (const float*)d_in[8];
    const float* fc_w2  = (const float*)d_in[9];
    const float* fc_b2  = (const float*)d_in[10];
    const float* dec_w  = (const float*)d_in[11];
    const float* dec_b  = (const float*)d_in[12];
    float* out = (float*)d_out;

    float* ws   = (float*)d_ws;
    float* Z    = ws;                 // R*L
    float* ylin = Z + R * L;          // R*H
    float* xlin = ylin + R * H;       // R*H
    float* hsum = xlin + R * H;       // R*H

    k_proj_lin<<<R / 2, 256, 0, stream>>>(X, proj_w, proj_b, rn_w1, rn_b1, Z, ylin, xlin, out);
    k_pairsort<<<B * H, 256, 0, stream>>>(xlin, ylin, hsum);
    k_post<false><<<R / 8, 256, 0, stream>>>(hsum, rn_w2, rn_b2, fc_w1, fc_b1, fc_w2, fc_b2,
                                             rn_w1 + 2 * L * H, rn_b1 + H, Z, ylin, xlin,
                                             nullptr, nullptr, nullptr);
    k_pairsort<<<B * H, 256, 0, stream>>>(xlin, ylin, hsum);
    k_post<true><<<R / 8, 256, 0, stream>>>(hsum, rn_w2 + H * L, rn_b2 + L,
                                            fc_w1 + L * H, fc_b1 + H, fc_w2 + H * L, fc_b2 + L,
                                            nullptr, nullptr, Z, nullptr, nullptr,
                                            dec_w, dec_b, out);
}